// Round 7
// baseline (605.928 us; speedup 1.0000x reference)
//
#include <hip/hip_runtime.h>
#include <cmath>

// Persistent weight-stationary LSTM decode. B=64, H=2048, steps=30.
// gates_t = W_sum @ h_t (t>=1, since x_t == h_t), W_hh @ h_0 at t=0.
// One block per CU (grid=256); weights live in LDS as fp16 MFMA A-frags.
//
// v11: OPTIMISTIC sentinel sync.
// v10 post-mortem: all-atomic h loads killed XCD-L2 amortization (each CU
// fetched its slice from LLC individually: FETCH 98->131MB, WRITE 9.8->38MB,
// dur +44%). v11 keeps v10's zero-RTT detection but restores the cacheable
// fast path:
//  - h slots 1..steps-1 pre-filled with 0xFFFF sentinel (all-ones f16 NaN,
//    unreachable from tanh*sigmoid outputs or the token cast).
//  - producer: two 8B agent-scope stores. NO vmcnt, NO flag: w0/w1 return
//    to compute immediately after issuing the stores.
//  - consumer: issue all 32 piece-loads as PLAIN CACHEABLE loads (v9's
//    path, XCD-L2 amortized), pinned by sched_barrier(0); validate per
//    piece interleaved with the MFMA loop; ONLY stale words re-fetched
//    via agent-scope atomic (bypasses the stale L1/L2 line; registers
//    keep the value, the stale line is never re-read).
// Serial chain per step: producer tail -> store visible -> retry-hit.
// (v9 additionally had vmcnt ack + flag visible + poll detect.)

#define HID   2048
#define BATCH 64
#define G4    8192
#define NCU   256                 // persistent grid size == CU count
#define HGRP  (HID * BATCH / 8)   // half8 groups per h slot
#define SENT  0xFFFFFFFFFFFFFFFFull

typedef __attribute__((ext_vector_type(8))) _Float16 half8;
typedef __attribute__((ext_vector_type(4))) float f32x4;

// LDS layout (bytes):
//   [0,      131072)  Wlds : half8 frags [(mt*64+kt)*64+lane]
//   [131072, 155648)  red4 : f32x4 [(srow*4+p)*64+lane]  (6 srows, 24KB)
#define LDS_BYTES 155648

// ---- init: slot0 <- token (B-frag layout); slots 1..steps-1 <- sentinel;
//      bsum <- bih+bhh. grid = 64*steps blocks x 256. ----
__global__ void k_init(const float* __restrict__ token, const float* __restrict__ bih,
                       const float* __restrict__ bhh, half8* __restrict__ hbuf8,
                       float* __restrict__ bsum) {
    int slot = blockIdx.x >> 6;
    int g = (blockIdx.x & 63) * 256 + threadIdx.x;   // [0, 16384)
    if (slot == 0) {
        int l = g & 63, nt = (g >> 6) & 3, kt = g >> 8;
        int n = nt * 16 + (l & 15);
        int k0 = kt * 32 + (l >> 4) * 8;
        const float4* ps = (const float4*)(token + (size_t)n * HID + k0);
        float4 a = ps[0], b = ps[1];
        half8 v;
        v[0]=(_Float16)a.x; v[1]=(_Float16)a.y; v[2]=(_Float16)a.z; v[3]=(_Float16)a.w;
        v[4]=(_Float16)b.x; v[5]=(_Float16)b.y; v[6]=(_Float16)b.z; v[7]=(_Float16)b.w;
        hbuf8[g] = v;
        if (g < G4) bsum[g] = bih[g] + bhh[g];
    } else {
        unsigned long long* d =
            (unsigned long long*)(hbuf8 + (size_t)slot * HGRP + g);
        d[0] = SENT; d[1] = SENT;
    }
}

// ---- the persistent kernel ----
__global__ __launch_bounds__(512, 2)
void k_lstm(const float* __restrict__ wih, const float* __restrict__ whh,
            const float* __restrict__ bsum, const float* __restrict__ wout,
            _Float16* __restrict__ hbuf,     // (steps+1) slots, fragment layout
            float* __restrict__ ypart,       // [steps][NCU][64]
            int steps) {
    extern __shared__ char smem[];
    half8* Wlds = (half8*)smem;
    f32x4* red4 = (f32x4*)(smem + 131072);

    const int tid  = threadIdx.x;
    const int blk  = blockIdx.x;
    const int lane = tid & 63;
    const int w    = tid >> 6;        // wave 0..7
    const int half = w & 1;           // n-tile pair: nt in {2*half, 2*half+1}
    const int ks   = w >> 1;          // k-split slice 0..3 (512 k each)
    const int q    = lane >> 4;       // C-frag row quad 0..3
    const int col  = lane & 15;       // C-frag col (n within tile)

    // prologue: stage W_hh rows for this block's 32 gate-rows as fp16 A-frags
    for (int idx = tid; idx < 2 * 64 * 64; idx += 512) {
        int l = idx & 63, kt = (idx >> 6) & 63, m2 = idx >> 12;
        int m = l & 15;
        int gate = m2 * 2 + (m >> 3);
        int row  = gate * HID + blk * 8 + (m & 7);
        int colw = kt * 32 + (l >> 4) * 8;
        const float4* p = (const float4*)(whh + (size_t)row * HID + colw);
        float4 a = p[0], b = p[1];
        half8 v;
        v[0]=(_Float16)a.x; v[1]=(_Float16)a.y; v[2]=(_Float16)a.z; v[3]=(_Float16)a.w;
        v[4]=(_Float16)b.x; v[5]=(_Float16)b.y; v[6]=(_Float16)b.z; v[7]=(_Float16)b.w;
        Wlds[idx] = v;
    }

    // pointwise-wave (w<2) per-lane constants / state:
    //   rows owned pre-shuffle: mt0 rows 4q+r (biasA), mt1 rows 16+4q+r (biasB)
    //   units owned post-shuffle: (q&1)*4 + r; batch n = half*32 + (q>>1)*16 + col
    float biasA[4] = {0,0,0,0}, biasB[4] = {0,0,0,0}, wj4[4] = {0,0,0,0};
    float c4[4] = {0.0f, 0.0f, 0.0f, 0.0f};
    if (w < 2) {
        #pragma unroll
        for (int r = 0; r < 4; ++r) {
            int rA = 4 * q + r;            // gates row, mt0 (0..15)
            int rB = 16 + 4 * q + r;       // gates row, mt1 (16..31)
            biasA[r] = bsum[(rA >> 3) * HID + blk * 8 + (rA & 7)];
            biasB[r] = bsum[(rB >> 3) * HID + blk * 8 + (rB & 7)];
            wj4[r]   = wout[blk * 8 + (q & 1) * 4 + r];
        }
    }
    __syncthreads();

    for (int t = 0; t < steps; ++t) {
        const _Float16* hslot = hbuf + (size_t)t * HID * BATCH;
        const int ktb = ks * 16;
        // ---- issue ALL 64 8B h-word loads back-to-back, PLAIN CACHEABLE
        //      (XCD-L2 amortized; fresh slot per step => no stale-hit on the
        //      first read). piece p = 2*kk+j -> words 2p, 2p+1.
        unsigned long long b64[64];
        #pragma unroll
        for (int p = 0; p < 32; ++p) {
            int kk = p >> 1, j = p & 1;
            const unsigned long long* wp = (const unsigned long long*)
                (hslot + (size_t)(((ktb + kk) * 4 + half * 2 + j) * 64 + lane) * 8);
            b64[2 * p + 0] = wp[0];
            b64[2 * p + 1] = wp[1];
        }
        __builtin_amdgcn_sched_barrier(0);   // loads stay issued here, not sunk
        // acc: (mt, nt = 2*half + j)
        f32x4 a00 = {0,0,0,0}, a01 = {0,0,0,0}, a10 = {0,0,0,0}, a11 = {0,0,0,0};
        #pragma unroll
        for (int kk = 0; kk < 16; ++kk) {
            int kt = ktb + kk;
            // validate the two pieces this kk consumes; stale words re-fetched
            // at agent scope (bypasses the stale L1/L2 line).
            #pragma unroll
            for (int j = 0; j < 2; ++j) {
                int p = 2 * kk + j;
                const unsigned long long* wp = (const unsigned long long*)
                    (hslot + (size_t)((kt * 4 + half * 2 + j) * 64 + lane) * 8);
                while (!__all((b64[2 * p] != SENT) & (b64[2 * p + 1] != SENT))) {
                    b64[2 * p + 0] = __hip_atomic_load(wp, __ATOMIC_RELAXED,
                                                       __HIP_MEMORY_SCOPE_AGENT);
                    b64[2 * p + 1] = __hip_atomic_load(wp + 1, __ATOMIC_RELAXED,
                                                       __HIP_MEMORY_SCOPE_AGENT);
                }
            }
            half8 av0 = Wlds[(kt) * 64 + lane];            // mt=0
            half8 av1 = Wlds[(64 + kt) * 64 + lane];       // mt=1
            union { unsigned long long u[2]; half8 h; } c0, c1;
            c0.u[0] = b64[4 * kk + 0]; c0.u[1] = b64[4 * kk + 1];
            c1.u[0] = b64[4 * kk + 2]; c1.u[1] = b64[4 * kk + 3];
            a00 = __builtin_amdgcn_mfma_f32_16x16x32_f16(av0, c0.h, a00, 0, 0, 0);
            a01 = __builtin_amdgcn_mfma_f32_16x16x32_f16(av0, c1.h, a01, 0, 0, 0);
            a10 = __builtin_amdgcn_mfma_f32_16x16x32_f16(av1, c0.h, a10, 0, 0, 0);
            a11 = __builtin_amdgcn_mfma_f32_16x16x32_f16(av1, c1.h, a11, 0, 0, 0);
        }
        // ---- 2-barrier k-split reduce (4 slices) ----
        if (ks == 1 || ks == 3) {
            int srow = (ks == 3 ? 2 : 0) + half;           // w2,w3 -> 0,1; w6,w7 -> 2,3
            red4[(srow * 4 + 0) * 64 + lane] = a00;
            red4[(srow * 4 + 1) * 64 + lane] = a01;
            red4[(srow * 4 + 2) * 64 + lane] = a10;
            red4[(srow * 4 + 3) * 64 + lane] = a11;
        }
        __syncthreads();                                   // bar1
        if (ks == 0) {
            int srow = half;
            a00 += red4[(srow * 4 + 0) * 64 + lane];
            a01 += red4[(srow * 4 + 1) * 64 + lane];
            a10 += red4[(srow * 4 + 2) * 64 + lane];
            a11 += red4[(srow * 4 + 3) * 64 + lane];
        } else if (ks == 2) {
            int srow = 2 + half;
            a00 += red4[(srow * 4 + 0) * 64 + lane];
            a01 += red4[(srow * 4 + 1) * 64 + lane];
            a10 += red4[(srow * 4 + 2) * 64 + lane];
            a11 += red4[(srow * 4 + 3) * 64 + lane];
            int sdst = 4 + half;
            red4[(sdst * 4 + 0) * 64 + lane] = a00;
            red4[(sdst * 4 + 1) * 64 + lane] = a01;
            red4[(sdst * 4 + 2) * 64 + lane] = a10;
            red4[(sdst * 4 + 3) * 64 + lane] = a11;
        }
        __syncthreads();                                   // bar2
        if (w < 2) {
            int srow = 4 + half;
            a00 += red4[(srow * 4 + 0) * 64 + lane];
            a01 += red4[(srow * 4 + 1) * 64 + lane];
            a10 += red4[(srow * 4 + 2) * 64 + lane];
            a11 += red4[(srow * 4 + 3) * 64 + lane];
            // bias (per gates-row; same row for both n-tiles)
            #pragma unroll
            for (int r = 0; r < 4; ++r) {
                a00[r] += biasA[r]; a01[r] += biasA[r];
                a10[r] += biasB[r]; a11[r] += biasB[r];
            }
            // cross-half exchange: partner lane^32 holds the other gate pair.
            // q<2 own (i,g) rows, partner has (f,o); q>=2 own (f,o), partner (i,g).
            float x00[4], x01[4], x10[4], x11[4];
            #pragma unroll
            for (int r = 0; r < 4; ++r) {
                x00[r] = __shfl_xor(a00[r], 32);
                x01[r] = __shfl_xor(a01[r], 32);
                x10[r] = __shfl_xor(a10[r], 32);
                x11[r] = __shfl_xor(a11[r], 32);
            }
            const bool lo = (lane < 32);   // q<2: handle n_lo via a00/a10 family
            float hv[4];
            #pragma unroll
            for (int r = 0; r < 4; ++r) {
                float gi = lo ? a00[r] : x01[r];
                float gf = lo ? x00[r] : a01[r];
                float gg = lo ? a10[r] : x11[r];
                float go = lo ? x10[r] : a11[r];
                float iv = 1.0f / (1.0f + __expf(-gi));
                float fv = 1.0f / (1.0f + __expf(-gf));
                float eg = __expf(2.0f * gg);
                float gv = 1.0f - 2.0f / (eg + 1.0f);      // tanh(gg)
                float ov = 1.0f / (1.0f + __expf(-go));
                c4[r] = fv * c4[r] + iv * gv;
                float ec = __expf(2.0f * c4[r]);
                float th = 1.0f - 2.0f / (ec + 1.0f);      // tanh(c)
                hv[r] = ov * th;
            }
            if (t < steps - 1) {
                // pack 4 f16 -> one 8B agent-scope store; lane pairs (q0,q1)
                // and (q2,q3) fill each 16B piece (units 0-3 | 4-7).
                // Sentinel protocol: no vmcnt, no flag -- the store IS the signal.
                union { unsigned short us[4]; unsigned long long ull; } pk;
                #pragma unroll
                for (int r = 0; r < 4; ++r) {
                    _Float16 hf = (_Float16)hv[r];
                    pk.us[r] = *(unsigned short*)&hf;
                }
                const int nt = half * 2 + (q >> 1);        // global n-tile
                const size_t g = (size_t)((blk >> 2) * 4 + nt) * 64
                               + (blk & 3) * 16 + col;
                unsigned long long* dst = (unsigned long long*)
                    (hbuf + (size_t)(t + 1) * HID * BATCH + g * 8) + (q & 1);
                __hip_atomic_store(dst, pk.ull, __ATOMIC_RELAXED,
                                   __HIP_MEMORY_SCOPE_AGENT);
            }
            // y partial (off the critical path)
            float yp = wj4[0] * hv[0] + wj4[1] * hv[1]
                     + wj4[2] * hv[2] + wj4[3] * hv[3];
            yp += __shfl_xor(yp, 16);                      // combine unit halves
            if ((q & 1) == 0)
                ypart[((size_t)t * NCU + blk) * 64
                      + half * 32 + (q >> 1) * 16 + col] = yp;
        }
        if (t == 0) {
            // upgrade Wlds in place: W_hh -> W_sum (+= W_ih); must complete in
            // ALL waves before any wave's step-1 MFMA -> block barrier after.
            for (int idx = tid; idx < 2 * 64 * 64; idx += 512) {
                int l = idx & 63, kt = (idx >> 6) & 63, m2 = idx >> 12;
                int m = l & 15;
                int gate = m2 * 2 + (m >> 3);
                int row  = gate * HID + blk * 8 + (m & 7);
                int colw = kt * 32 + (l >> 4) * 8;
                const float4* p = (const float4*)(wih + (size_t)row * HID + colw);
                float4 a = p[0], b = p[1];
                half8 v = Wlds[idx];
                v[0] = (_Float16)((float)v[0] + a.x); v[1] = (_Float16)((float)v[1] + a.y);
                v[2] = (_Float16)((float)v[2] + a.z); v[3] = (_Float16)((float)v[3] + a.w);
                v[4] = (_Float16)((float)v[4] + b.x); v[5] = (_Float16)((float)v[5] + b.y);
                v[6] = (_Float16)((float)v[6] + b.z); v[7] = (_Float16)((float)v[7] + b.w);
                Wlds[idx] = v;
            }
            __syncthreads();
        }
    }
}

// ---- final: out[b][t] = bout + sum over 256 CU partials ----
__global__ __launch_bounds__(512)
void k_yout(const float* __restrict__ ypart, const float* __restrict__ bout,
            float* __restrict__ out, int steps) {
    __shared__ float red[8][64];
    int t = blockIdx.x;
    int tid = threadIdx.x;
    int b = tid & 63, ch = tid >> 6;               // 8 chunks x 32 CUs
    const float* p = ypart + (size_t)t * NCU * 64 + b;
    float s = 0.0f;
    #pragma unroll 8
    for (int cu = ch * 32; cu < ch * 32 + 32; ++cu) s += p[(size_t)cu * 64];
    red[ch][b] = s;
    __syncthreads();
    if (tid < 64) {
        float r = bout[0];
        #pragma unroll
        for (int u = 0; u < 8; ++u) r += red[u][tid];
        out[(size_t)tid * steps + t] = r;
    }
}

extern "C" void kernel_launch(void* const* d_in, const int* in_sizes, int n_in,
                              void* d_out, int out_size, void* d_ws, size_t ws_size,
                              hipStream_t stream) {
    const float* token = (const float*)d_in[0];
    const float* wih   = (const float*)d_in[2];
    const float* whh   = (const float*)d_in[3];
    const float* bih   = (const float*)d_in[4];
    const float* bhh   = (const float*)d_in[5];
    const float* wout  = (const float*)d_in[6];
    const float* bout  = (const float*)d_in[7];
    float* out = (float*)d_out;
    const int steps = out_size / BATCH;            // 30

    char* ws = (char*)d_ws;
    size_t off = 0;
    auto carve = [&](size_t bytes) -> void* {
        void* p = ws + off;
        off = (off + bytes + 255) & ~(size_t)255;
        return p;
    };
    _Float16* hbuf  = (_Float16*)carve((size_t)(steps + 1) * HID * BATCH * 2); // ~8 MB
    float*    bsum  = (float*)carve((size_t)G4 * 4);                   // 32 KB
    float*    ypart = (float*)carve((size_t)steps * NCU * 64 * 4);     // ~2 MB

    hipFuncSetAttribute(reinterpret_cast<const void*>(&k_lstm),
                        hipFuncAttributeMaxDynamicSharedMemorySize, LDS_BYTES);

    k_init<<<dim3(64 * steps), dim3(256), 0, stream>>>(
        token, bih, bhh, (half8*)hbuf, bsum);

    k_lstm<<<dim3(NCU), dim3(512), LDS_BYTES, stream>>>(
        wih, whh, bsum, wout, hbuf, ypart, steps);

    k_yout<<<dim3(steps), dim3(512), 0, stream>>>(ypart, bout, out, steps);
}

// Round 8
// 448.552 us; speedup vs baseline: 1.3509x; 1.3509x over previous
//
#include <hip/hip_runtime.h>
#include <cmath>

// Persistent weight-stationary LSTM decode. B=64, H=2048, steps=30.
// gates_t = W_sum @ h_t (t>=1, since x_t == h_t), W_hh @ h_0 at t=0.
// One block per CU (grid=256); weights live in LDS as fp16 MFMA A-frags.
//
// v12 = v9 (best kernel, 327us) + BUSY-SPIN instead of s_sleep.
// v10/v11 post-mortems: flag-free sentinel sync destroys XCD-L2
// amortization (per-CU LLC fetches, FETCH 98->650MB) and serializes
// 32 retry RTTs -- flag+cacheable (v5/v9) is the right topology.
// Surviving anomaly: all pipes ~92% idle yet step=11us vs ~3.5us of
// chain cost at 2.4GHz; counters imply effective clock ~715MHz. Theory:
// waves s_sleep most of the step -> governor sees an idle engine ->
// low DPM state multiplies EVERY serial component ~3x. This version
// burns dependent FMAs between flag polls (4 indep chains x 16) so the
// engine never looks idle. One variable changed vs v9.

#define HID   2048
#define BATCH 64
#define G4    8192
#define NCU   256                 // persistent grid size == CU count
#define HGRP  (HID * BATCH / 8)   // half8 groups per h slot
#define NFLAGS 512                // [half][block]

typedef __attribute__((ext_vector_type(8))) _Float16 half8;
typedef __attribute__((ext_vector_type(4))) float f32x4;

// LDS layout (bytes):
//   [0,      131072)  Wlds : half8 frags [(mt*64+kt)*64+lane]
//   [131072, 155648)  red4 : f32x4 [(srow*4+p)*64+lane]  (6 srows, 24KB)
#define LDS_BYTES 155648

// ---- init: pack token -> h slot 0 (B-fragment layout), bsum, flags ----
__global__ void k_init(const float* __restrict__ token, const float* __restrict__ bih,
                       const float* __restrict__ bhh, half8* __restrict__ h0p,
                       float* __restrict__ bsum, unsigned* __restrict__ flags) {
    int g = blockIdx.x * 256 + threadIdx.x;          // [0, 16384)
    int l = g & 63, nt = (g >> 6) & 3, kt = g >> 8;
    int n = nt * 16 + (l & 15);
    int k0 = kt * 32 + (l >> 4) * 8;
    const float4* ps = (const float4*)(token + (size_t)n * HID + k0);
    float4 a = ps[0], b = ps[1];
    half8 v;
    v[0]=(_Float16)a.x; v[1]=(_Float16)a.y; v[2]=(_Float16)a.z; v[3]=(_Float16)a.w;
    v[4]=(_Float16)b.x; v[5]=(_Float16)b.y; v[6]=(_Float16)b.z; v[7]=(_Float16)b.w;
    h0p[g] = v;
    if (g < G4) bsum[g] = bih[g] + bhh[g];
    if (g < NFLAGS) flags[g] = 0u;
}

// ---- the persistent kernel ----
__global__ __launch_bounds__(512, 2)
void k_lstm(const float* __restrict__ wih, const float* __restrict__ whh,
            const float* __restrict__ bsum, const float* __restrict__ wout,
            _Float16* __restrict__ hbuf,     // (steps+1) slots, fragment layout
            float* __restrict__ ypart,       // [steps][NCU][64]
            unsigned* __restrict__ flags, int steps) {
    extern __shared__ char smem[];
    half8* Wlds = (half8*)smem;
    f32x4* red4 = (f32x4*)(smem + 131072);

    const int tid  = threadIdx.x;
    const int blk  = blockIdx.x;
    const int lane = tid & 63;
    const int w    = tid >> 6;        // wave 0..7
    const int half = w & 1;           // n-tile pair: nt in {2*half, 2*half+1}
    const int ks   = w >> 1;          // k-split slice 0..3 (512 k each)
    const int q    = lane >> 4;       // C-frag row quad 0..3
    const int col  = lane & 15;       // C-frag col (n within tile)

    // prologue: stage W_hh rows for this block's 32 gate-rows as fp16 A-frags
    for (int idx = tid; idx < 2 * 64 * 64; idx += 512) {
        int l = idx & 63, kt = (idx >> 6) & 63, m2 = idx >> 12;
        int m = l & 15;
        int gate = m2 * 2 + (m >> 3);
        int row  = gate * HID + blk * 8 + (m & 7);
        int colw = kt * 32 + (l >> 4) * 8;
        const float4* p = (const float4*)(whh + (size_t)row * HID + colw);
        float4 a = p[0], b = p[1];
        half8 v;
        v[0]=(_Float16)a.x; v[1]=(_Float16)a.y; v[2]=(_Float16)a.z; v[3]=(_Float16)a.w;
        v[4]=(_Float16)b.x; v[5]=(_Float16)b.y; v[6]=(_Float16)b.z; v[7]=(_Float16)b.w;
        Wlds[idx] = v;
    }

    // pointwise-wave (w<2) per-lane constants / state:
    //   rows owned pre-shuffle: mt0 rows 4q+r (biasA), mt1 rows 16+4q+r (biasB)
    //   units owned post-shuffle: (q&1)*4 + r; batch n = half*32 + (q>>1)*16 + col
    float biasA[4] = {0,0,0,0}, biasB[4] = {0,0,0,0}, wj4[4] = {0,0,0,0};
    float c4[4] = {0.0f, 0.0f, 0.0f, 0.0f};
    if (w < 2) {
        #pragma unroll
        for (int r = 0; r < 4; ++r) {
            int rA = 4 * q + r;            // gates row, mt0 (0..15)
            int rB = 16 + 4 * q + r;       // gates row, mt1 (16..31)
            biasA[r] = bsum[(rA >> 3) * HID + blk * 8 + (rA & 7)];
            biasB[r] = bsum[(rB >> 3) * HID + blk * 8 + (rB & 7)];
            wj4[r]   = wout[blk * 8 + (q & 1) * 4 + r];
        }
    }
    __syncthreads();

    // busy-spin fuel: 4 independent FMA chains (never observable except via
    // the asm sink below; keeps the SIMD issue slots hot during waits).
    float d0 = (float)lane + 1.0f, d1 = d0 * 1.5f, d2 = d0 * 2.5f, d3 = d0 * 3.5f;

    for (int t = 0; t < steps; ++t) {
        if (t) {
            // per-slice wait: wave (ks,half) consumes pieces (p, n in its half)
            // for producers p in [ks*64, ks*64+64). Lane li waits its flag.
            // BUSY-SPIN: dependent-FMA burn between polls (no s_sleep) so the
            // power governor never sees an idle engine (anti-throttle).
            while (__hip_atomic_load(&flags[half * NCU + ks * 64 + lane],
                                     __ATOMIC_RELAXED, __HIP_MEMORY_SCOPE_AGENT)
                   < (unsigned)t) {
                #pragma unroll
                for (int it = 0; it < 16; ++it) {
                    d0 = __builtin_fmaf(d0, 1.0000001f, 1e-20f);
                    d1 = __builtin_fmaf(d1, 1.0000001f, 1e-20f);
                    d2 = __builtin_fmaf(d2, 1.0000001f, 1e-20f);
                    d3 = __builtin_fmaf(d3, 1.0000001f, 1e-20f);
                }
            }
            asm volatile("" :: "v"(d0), "v"(d1), "v"(d2), "v"(d3));
            asm volatile("" ::: "memory");   // no h loads hoisted above the spin
        }
        const half8* hp = (const half8*)(hbuf + (size_t)t * HID * BATCH);
        const int ktb = ks * 16;
        // ---- issue ALL 32 B-frag loads back-to-back (max MLP) ----
        half8 bfr[32];
        #pragma unroll
        for (int kk = 0; kk < 16; ++kk) {
            bfr[2 * kk + 0] = hp[((ktb + kk) * 4 + half * 2 + 0) * 64 + lane];
            bfr[2 * kk + 1] = hp[((ktb + kk) * 4 + half * 2 + 1) * 64 + lane];
        }
        // acc: (mt, nt = 2*half + j)
        f32x4 a00 = {0,0,0,0}, a01 = {0,0,0,0}, a10 = {0,0,0,0}, a11 = {0,0,0,0};
        #pragma unroll
        for (int kk = 0; kk < 16; ++kk) {
            int kt = ktb + kk;
            half8 av0 = Wlds[(kt) * 64 + lane];            // mt=0
            half8 av1 = Wlds[(64 + kt) * 64 + lane];       // mt=1
            a00 = __builtin_amdgcn_mfma_f32_16x16x32_f16(av0, bfr[2 * kk + 0], a00, 0, 0, 0);
            a01 = __builtin_amdgcn_mfma_f32_16x16x32_f16(av0, bfr[2 * kk + 1], a01, 0, 0, 0);
            a10 = __builtin_amdgcn_mfma_f32_16x16x32_f16(av1, bfr[2 * kk + 0], a10, 0, 0, 0);
            a11 = __builtin_amdgcn_mfma_f32_16x16x32_f16(av1, bfr[2 * kk + 1], a11, 0, 0, 0);
        }
        // ---- 2-barrier k-split reduce (4 slices) ----
        if (ks == 1 || ks == 3) {
            int srow = (ks == 3 ? 2 : 0) + half;           // w2,w3 -> 0,1; w6,w7 -> 2,3
            red4[(srow * 4 + 0) * 64 + lane] = a00;
            red4[(srow * 4 + 1) * 64 + lane] = a01;
            red4[(srow * 4 + 2) * 64 + lane] = a10;
            red4[(srow * 4 + 3) * 64 + lane] = a11;
        }
        __syncthreads();                                   // bar1
        if (ks == 0) {
            int srow = half;
            a00 += red4[(srow * 4 + 0) * 64 + lane];
            a01 += red4[(srow * 4 + 1) * 64 + lane];
            a10 += red4[(srow * 4 + 2) * 64 + lane];
            a11 += red4[(srow * 4 + 3) * 64 + lane];
        } else if (ks == 2) {
            int srow = 2 + half;
            a00 += red4[(srow * 4 + 0) * 64 + lane];
            a01 += red4[(srow * 4 + 1) * 64 + lane];
            a10 += red4[(srow * 4 + 2) * 64 + lane];
            a11 += red4[(srow * 4 + 3) * 64 + lane];
            int sdst = 4 + half;
            red4[(sdst * 4 + 0) * 64 + lane] = a00;
            red4[(sdst * 4 + 1) * 64 + lane] = a01;
            red4[(sdst * 4 + 2) * 64 + lane] = a10;
            red4[(sdst * 4 + 3) * 64 + lane] = a11;
        }
        __syncthreads();                                   // bar2
        if (w < 2) {
            int srow = 4 + half;
            a00 += red4[(srow * 4 + 0) * 64 + lane];
            a01 += red4[(srow * 4 + 1) * 64 + lane];
            a10 += red4[(srow * 4 + 2) * 64 + lane];
            a11 += red4[(srow * 4 + 3) * 64 + lane];
            // bias (per gates-row; same row for both n-tiles)
            #pragma unroll
            for (int r = 0; r < 4; ++r) {
                a00[r] += biasA[r]; a01[r] += biasA[r];
                a10[r] += biasB[r]; a11[r] += biasB[r];
            }
            // cross-half exchange: partner lane^32 holds the other gate pair.
            // q<2 own (i,g) rows, partner has (f,o); q>=2 own (f,o), partner (i,g).
            float x00[4], x01[4], x10[4], x11[4];
            #pragma unroll
            for (int r = 0; r < 4; ++r) {
                x00[r] = __shfl_xor(a00[r], 32);
                x01[r] = __shfl_xor(a01[r], 32);
                x10[r] = __shfl_xor(a10[r], 32);
                x11[r] = __shfl_xor(a11[r], 32);
            }
            const bool lo = (lane < 32);   // q<2: handle n_lo via a00/a10 family
            float hv[4];
            #pragma unroll
            for (int r = 0; r < 4; ++r) {
                float gi = lo ? a00[r] : x01[r];
                float gf = lo ? x00[r] : a01[r];
                float gg = lo ? a10[r] : x11[r];
                float go = lo ? x10[r] : a11[r];
                float iv = 1.0f / (1.0f + __expf(-gi));
                float fv = 1.0f / (1.0f + __expf(-gf));
                float eg = __expf(2.0f * gg);
                float gv = 1.0f - 2.0f / (eg + 1.0f);      // tanh(gg)
                float ov = 1.0f / (1.0f + __expf(-go));
                c4[r] = fv * c4[r] + iv * gv;
                float ec = __expf(2.0f * c4[r]);
                float th = 1.0f - 2.0f / (ec + 1.0f);      // tanh(c)
                hv[r] = ov * th;
            }
            if (t < steps - 1) {
                // pack 4 f16 -> one 8B agent-scope store; lane pairs (q0,q1)
                // and (q2,q3) fill each 16B piece (units 0-3 | 4-7).
                union { unsigned short us[4]; unsigned long long ull; } pk;
                #pragma unroll
                for (int r = 0; r < 4; ++r) {
                    _Float16 hf = (_Float16)hv[r];
                    pk.us[r] = *(unsigned short*)&hf;
                }
                const int nt = half * 2 + (q >> 1);        // global n-tile
                const size_t g = (size_t)((blk >> 2) * 4 + nt) * 64
                               + (blk & 3) * 16 + col;
                unsigned long long* dst = (unsigned long long*)
                    (hbuf + (size_t)(t + 1) * HID * BATCH + g * 8) + (q & 1);
                __hip_atomic_store(dst, pk.ull, __ATOMIC_RELAXED,
                                   __HIP_MEMORY_SCOPE_AGENT);
                asm volatile("s_waitcnt vmcnt(0)" ::: "memory");  // h at coherence pt
                if (lane == 0)
                    __hip_atomic_store(&flags[half * NCU + blk], (unsigned)(t + 1),
                                       __ATOMIC_RELAXED, __HIP_MEMORY_SCOPE_AGENT);
            }
            // y partial (off the critical path, after flag release)
            float yp = wj4[0] * hv[0] + wj4[1] * hv[1]
                     + wj4[2] * hv[2] + wj4[3] * hv[3];
            yp += __shfl_xor(yp, 16);                      // combine unit halves
            if ((q & 1) == 0)
                ypart[((size_t)t * NCU + blk) * 64
                      + half * 32 + (q >> 1) * 16 + col] = yp;
        }
        if (t == 0) {
            // upgrade Wlds in place: W_hh -> W_sum (+= W_ih); must complete in
            // ALL waves before any wave's step-1 MFMA -> block barrier after.
            for (int idx = tid; idx < 2 * 64 * 64; idx += 512) {
                int l = idx & 63, kt = (idx >> 6) & 63, m2 = idx >> 12;
                int m = l & 15;
                int gate = m2 * 2 + (m >> 3);
                int row  = gate * HID + blk * 8 + (m & 7);
                int colw = kt * 32 + (l >> 4) * 8;
                const float4* p = (const float4*)(wih + (size_t)row * HID + colw);
                float4 a = p[0], b = p[1];
                half8 v = Wlds[idx];
                v[0] = (_Float16)((float)v[0] + a.x); v[1] = (_Float16)((float)v[1] + a.y);
                v[2] = (_Float16)((float)v[2] + a.z); v[3] = (_Float16)((float)v[3] + a.w);
                v[4] = (_Float16)((float)v[4] + b.x); v[5] = (_Float16)((float)v[5] + b.y);
                v[6] = (_Float16)((float)v[6] + b.z); v[7] = (_Float16)((float)v[7] + b.w);
                Wlds[idx] = v;
            }
            __syncthreads();
        }
    }
}

// ---- final: out[b][t] = bout + sum over 256 CU partials ----
__global__ __launch_bounds__(512)
void k_yout(const float* __restrict__ ypart, const float* __restrict__ bout,
            float* __restrict__ out, int steps) {
    __shared__ float red[8][64];
    int t = blockIdx.x;
    int tid = threadIdx.x;
    int b = tid & 63, ch = tid >> 6;               // 8 chunks x 32 CUs
    const float* p = ypart + (size_t)t * NCU * 64 + b;
    float s = 0.0f;
    #pragma unroll 8
    for (int cu = ch * 32; cu < ch * 32 + 32; ++cu) s += p[(size_t)cu * 64];
    red[ch][b] = s;
    __syncthreads();
    if (tid < 64) {
        float r = bout[0];
        #pragma unroll
        for (int u = 0; u < 8; ++u) r += red[u][tid];
        out[(size_t)tid * steps + t] = r;
    }
}

extern "C" void kernel_launch(void* const* d_in, const int* in_sizes, int n_in,
                              void* d_out, int out_size, void* d_ws, size_t ws_size,
                              hipStream_t stream) {
    const float* token = (const float*)d_in[0];
    const float* wih   = (const float*)d_in[2];
    const float* whh   = (const float*)d_in[3];
    const float* bih   = (const float*)d_in[4];
    const float* bhh   = (const float*)d_in[5];
    const float* wout  = (const float*)d_in[6];
    const float* bout  = (const float*)d_in[7];
    float* out = (float*)d_out;
    const int steps = out_size / BATCH;            // 30

    char* ws = (char*)d_ws;
    size_t off = 0;
    auto carve = [&](size_t bytes) -> void* {
        void* p = ws + off;
        off = (off + bytes + 255) & ~(size_t)255;
        return p;
    };
    _Float16* hbuf  = (_Float16*)carve((size_t)(steps + 1) * HID * BATCH * 2); // ~8 MB
    float*    bsum  = (float*)carve((size_t)G4 * 4);                   // 32 KB
    float*    ypart = (float*)carve((size_t)steps * NCU * 64 * 4);     // ~2 MB
    unsigned* flags = (unsigned*)carve(NFLAGS * 4);

    hipFuncSetAttribute(reinterpret_cast<const void*>(&k_lstm),
                        hipFuncAttributeMaxDynamicSharedMemorySize, LDS_BYTES);

    k_init<<<dim3(HGRP / 256), dim3(256), 0, stream>>>(
        token, bih, bhh, (half8*)hbuf, bsum, flags);

    k_lstm<<<dim3(NCU), dim3(512), LDS_BYTES, stream>>>(
        wih, whh, bsum, wout, hbuf, ypart, flags, steps);

    k_yout<<<dim3(steps), dim3(512), 0, stream>>>(ypart, bout, out, steps);
}

// Round 9
// 402.406 us; speedup vs baseline: 1.5058x; 1.1147x over previous
//
#include <hip/hip_runtime.h>
#include <cmath>

// Persistent weight-stationary LSTM decode. B=64, H=2048, steps=30.
// gates_t = W_sum @ h_t (t>=1, since x_t == h_t), W_hh @ h_0 at t=0.
// One block per CU (grid=256); weights live in LDS as fp16 MFMA A-frags.
//
// v13 = v9 + sched_barrier(0) pin between h-load issue and MFMA loop.
// Post-mortems: v8 (barriers/LDS-tail) neutral; v7 (pointwise) neutral;
// v12 (busy-spin) neutral with VALUBusy 2x => flag-wait is minor; v10/v11
// (flag-free sentinel) regress via lost L2 amortization. v9/v12 show
// VGPR=64: the bfr[32] prefetch keeps getting SUNK into the MFMA loop
// (pipeline depth ~1 => ~16 exposed LLC latencies per step = the bulk of
// the step period). v10/v11 proved sched_barrier(0) pins issue (VGPR=128)
// but conflated it with atomic traffic. This version runs the clean
// experiment: plain cacheable loads, all 32 issued back-to-back, pinned.
// Verification signal: VGPR >= ~160. One variable changed vs v9.

#define HID   2048
#define BATCH 64
#define G4    8192
#define NCU   256                 // persistent grid size == CU count
#define HGRP  (HID * BATCH / 8)   // half8 groups per h slot
#define NFLAGS 512                // [half][block]

typedef __attribute__((ext_vector_type(8))) _Float16 half8;
typedef __attribute__((ext_vector_type(4))) float f32x4;

// LDS layout (bytes):
//   [0,      131072)  Wlds : half8 frags [(mt*64+kt)*64+lane]
//   [131072, 155648)  red4 : f32x4 [(srow*4+p)*64+lane]  (6 srows, 24KB)
#define LDS_BYTES 155648

// ---- init: pack token -> h slot 0 (B-fragment layout), bsum, flags ----
__global__ void k_init(const float* __restrict__ token, const float* __restrict__ bih,
                       const float* __restrict__ bhh, half8* __restrict__ h0p,
                       float* __restrict__ bsum, unsigned* __restrict__ flags) {
    int g = blockIdx.x * 256 + threadIdx.x;          // [0, 16384)
    int l = g & 63, nt = (g >> 6) & 3, kt = g >> 8;
    int n = nt * 16 + (l & 15);
    int k0 = kt * 32 + (l >> 4) * 8;
    const float4* ps = (const float4*)(token + (size_t)n * HID + k0);
    float4 a = ps[0], b = ps[1];
    half8 v;
    v[0]=(_Float16)a.x; v[1]=(_Float16)a.y; v[2]=(_Float16)a.z; v[3]=(_Float16)a.w;
    v[4]=(_Float16)b.x; v[5]=(_Float16)b.y; v[6]=(_Float16)b.z; v[7]=(_Float16)b.w;
    h0p[g] = v;
    if (g < G4) bsum[g] = bih[g] + bhh[g];
    if (g < NFLAGS) flags[g] = 0u;
}

// ---- the persistent kernel ----
__global__ __launch_bounds__(512, 2)
void k_lstm(const float* __restrict__ wih, const float* __restrict__ whh,
            const float* __restrict__ bsum, const float* __restrict__ wout,
            _Float16* __restrict__ hbuf,     // (steps+1) slots, fragment layout
            float* __restrict__ ypart,       // [steps][NCU][64]
            unsigned* __restrict__ flags, int steps) {
    extern __shared__ char smem[];
    half8* Wlds = (half8*)smem;
    f32x4* red4 = (f32x4*)(smem + 131072);

    const int tid  = threadIdx.x;
    const int blk  = blockIdx.x;
    const int lane = tid & 63;
    const int w    = tid >> 6;        // wave 0..7
    const int half = w & 1;           // n-tile pair: nt in {2*half, 2*half+1}
    const int ks   = w >> 1;          // k-split slice 0..3 (512 k each)
    const int q    = lane >> 4;       // C-frag row quad 0..3
    const int col  = lane & 15;       // C-frag col (n within tile)

    // prologue: stage W_hh rows for this block's 32 gate-rows as fp16 A-frags
    for (int idx = tid; idx < 2 * 64 * 64; idx += 512) {
        int l = idx & 63, kt = (idx >> 6) & 63, m2 = idx >> 12;
        int m = l & 15;
        int gate = m2 * 2 + (m >> 3);
        int row  = gate * HID + blk * 8 + (m & 7);
        int colw = kt * 32 + (l >> 4) * 8;
        const float4* p = (const float4*)(whh + (size_t)row * HID + colw);
        float4 a = p[0], b = p[1];
        half8 v;
        v[0]=(_Float16)a.x; v[1]=(_Float16)a.y; v[2]=(_Float16)a.z; v[3]=(_Float16)a.w;
        v[4]=(_Float16)b.x; v[5]=(_Float16)b.y; v[6]=(_Float16)b.z; v[7]=(_Float16)b.w;
        Wlds[idx] = v;
    }

    // pointwise-wave (w<2) per-lane constants / state:
    //   rows owned pre-shuffle: mt0 rows 4q+r (biasA), mt1 rows 16+4q+r (biasB)
    //   units owned post-shuffle: (q&1)*4 + r; batch n = half*32 + (q>>1)*16 + col
    float biasA[4] = {0,0,0,0}, biasB[4] = {0,0,0,0}, wj4[4] = {0,0,0,0};
    float c4[4] = {0.0f, 0.0f, 0.0f, 0.0f};
    if (w < 2) {
        #pragma unroll
        for (int r = 0; r < 4; ++r) {
            int rA = 4 * q + r;            // gates row, mt0 (0..15)
            int rB = 16 + 4 * q + r;       // gates row, mt1 (16..31)
            biasA[r] = bsum[(rA >> 3) * HID + blk * 8 + (rA & 7)];
            biasB[r] = bsum[(rB >> 3) * HID + blk * 8 + (rB & 7)];
            wj4[r]   = wout[blk * 8 + (q & 1) * 4 + r];
        }
    }
    __syncthreads();

    for (int t = 0; t < steps; ++t) {
        if (t) {
            // per-slice wait: wave (ks,half) consumes pieces (p, n in its half)
            // for producers p in [ks*64, ks*64+64). Lane li waits its flag.
            while (__hip_atomic_load(&flags[half * NCU + ks * 64 + lane],
                                     __ATOMIC_RELAXED, __HIP_MEMORY_SCOPE_AGENT)
                   < (unsigned)t)
                __builtin_amdgcn_s_sleep(1);
            asm volatile("" ::: "memory");   // no h loads hoisted above the spin
        }
        const half8* hp = (const half8*)(hbuf + (size_t)t * HID * BATCH);
        const int ktb = ks * 16;
        // ---- issue ALL 32 B-frag loads back-to-back, then PIN them above
        //      the MFMA loop (sched_barrier). One LLC latency amortized over
        //      32 in-flight loads instead of ~16 exposed latencies. ----
        half8 bfr[32];
        #pragma unroll
        for (int kk = 0; kk < 16; ++kk) {
            bfr[2 * kk + 0] = hp[((ktb + kk) * 4 + half * 2 + 0) * 64 + lane];
            bfr[2 * kk + 1] = hp[((ktb + kk) * 4 + half * 2 + 1) * 64 + lane];
        }
        __builtin_amdgcn_sched_barrier(0);   // loads may not sink below here
        // acc: (mt, nt = 2*half + j)
        f32x4 a00 = {0,0,0,0}, a01 = {0,0,0,0}, a10 = {0,0,0,0}, a11 = {0,0,0,0};
        #pragma unroll
        for (int kk = 0; kk < 16; ++kk) {
            int kt = ktb + kk;
            half8 av0 = Wlds[(kt) * 64 + lane];            // mt=0
            half8 av1 = Wlds[(64 + kt) * 64 + lane];       // mt=1
            a00 = __builtin_amdgcn_mfma_f32_16x16x32_f16(av0, bfr[2 * kk + 0], a00, 0, 0, 0);
            a01 = __builtin_amdgcn_mfma_f32_16x16x32_f16(av0, bfr[2 * kk + 1], a01, 0, 0, 0);
            a10 = __builtin_amdgcn_mfma_f32_16x16x32_f16(av1, bfr[2 * kk + 0], a10, 0, 0, 0);
            a11 = __builtin_amdgcn_mfma_f32_16x16x32_f16(av1, bfr[2 * kk + 1], a11, 0, 0, 0);
        }
        // ---- 2-barrier k-split reduce (4 slices) ----
        if (ks == 1 || ks == 3) {
            int srow = (ks == 3 ? 2 : 0) + half;           // w2,w3 -> 0,1; w6,w7 -> 2,3
            red4[(srow * 4 + 0) * 64 + lane] = a00;
            red4[(srow * 4 + 1) * 64 + lane] = a01;
            red4[(srow * 4 + 2) * 64 + lane] = a10;
            red4[(srow * 4 + 3) * 64 + lane] = a11;
        }
        __syncthreads();                                   // bar1
        if (ks == 0) {
            int srow = half;
            a00 += red4[(srow * 4 + 0) * 64 + lane];
            a01 += red4[(srow * 4 + 1) * 64 + lane];
            a10 += red4[(srow * 4 + 2) * 64 + lane];
            a11 += red4[(srow * 4 + 3) * 64 + lane];
        } else if (ks == 2) {
            int srow = 2 + half;
            a00 += red4[(srow * 4 + 0) * 64 + lane];
            a01 += red4[(srow * 4 + 1) * 64 + lane];
            a10 += red4[(srow * 4 + 2) * 64 + lane];
            a11 += red4[(srow * 4 + 3) * 64 + lane];
            int sdst = 4 + half;
            red4[(sdst * 4 + 0) * 64 + lane] = a00;
            red4[(sdst * 4 + 1) * 64 + lane] = a01;
            red4[(sdst * 4 + 2) * 64 + lane] = a10;
            red4[(sdst * 4 + 3) * 64 + lane] = a11;
        }
        __syncthreads();                                   // bar2
        if (w < 2) {
            int srow = 4 + half;
            a00 += red4[(srow * 4 + 0) * 64 + lane];
            a01 += red4[(srow * 4 + 1) * 64 + lane];
            a10 += red4[(srow * 4 + 2) * 64 + lane];
            a11 += red4[(srow * 4 + 3) * 64 + lane];
            // bias (per gates-row; same row for both n-tiles)
            #pragma unroll
            for (int r = 0; r < 4; ++r) {
                a00[r] += biasA[r]; a01[r] += biasA[r];
                a10[r] += biasB[r]; a11[r] += biasB[r];
            }
            // cross-half exchange: partner lane^32 holds the other gate pair.
            // q<2 own (i,g) rows, partner has (f,o); q>=2 own (f,o), partner (i,g).
            float x00[4], x01[4], x10[4], x11[4];
            #pragma unroll
            for (int r = 0; r < 4; ++r) {
                x00[r] = __shfl_xor(a00[r], 32);
                x01[r] = __shfl_xor(a01[r], 32);
                x10[r] = __shfl_xor(a10[r], 32);
                x11[r] = __shfl_xor(a11[r], 32);
            }
            const bool lo = (lane < 32);   // q<2: handle n_lo via a00/a10 family
            float hv[4];
            #pragma unroll
            for (int r = 0; r < 4; ++r) {
                float gi = lo ? a00[r] : x01[r];
                float gf = lo ? x00[r] : a01[r];
                float gg = lo ? a10[r] : x11[r];
                float go = lo ? x10[r] : a11[r];
                float iv = 1.0f / (1.0f + __expf(-gi));
                float fv = 1.0f / (1.0f + __expf(-gf));
                float eg = __expf(2.0f * gg);
                float gv = 1.0f - 2.0f / (eg + 1.0f);      // tanh(gg)
                float ov = 1.0f / (1.0f + __expf(-go));
                c4[r] = fv * c4[r] + iv * gv;
                float ec = __expf(2.0f * c4[r]);
                float th = 1.0f - 2.0f / (ec + 1.0f);      // tanh(c)
                hv[r] = ov * th;
            }
            if (t < steps - 1) {
                // pack 4 f16 -> one 8B agent-scope store; lane pairs (q0,q1)
                // and (q2,q3) fill each 16B piece (units 0-3 | 4-7).
                union { unsigned short us[4]; unsigned long long ull; } pk;
                #pragma unroll
                for (int r = 0; r < 4; ++r) {
                    _Float16 hf = (_Float16)hv[r];
                    pk.us[r] = *(unsigned short*)&hf;
                }
                const int nt = half * 2 + (q >> 1);        // global n-tile
                const size_t g = (size_t)((blk >> 2) * 4 + nt) * 64
                               + (blk & 3) * 16 + col;
                unsigned long long* dst = (unsigned long long*)
                    (hbuf + (size_t)(t + 1) * HID * BATCH + g * 8) + (q & 1);
                __hip_atomic_store(dst, pk.ull, __ATOMIC_RELAXED,
                                   __HIP_MEMORY_SCOPE_AGENT);
                asm volatile("s_waitcnt vmcnt(0)" ::: "memory");  // h at coherence pt
                if (lane == 0)
                    __hip_atomic_store(&flags[half * NCU + blk], (unsigned)(t + 1),
                                       __ATOMIC_RELAXED, __HIP_MEMORY_SCOPE_AGENT);
            }
            // y partial (off the critical path, after flag release)
            float yp = wj4[0] * hv[0] + wj4[1] * hv[1]
                     + wj4[2] * hv[2] + wj4[3] * hv[3];
            yp += __shfl_xor(yp, 16);                      // combine unit halves
            if ((q & 1) == 0)
                ypart[((size_t)t * NCU + blk) * 64
                      + half * 32 + (q >> 1) * 16 + col] = yp;
        }
        if (t == 0) {
            // upgrade Wlds in place: W_hh -> W_sum (+= W_ih); must complete in
            // ALL waves before any wave's step-1 MFMA -> block barrier after.
            for (int idx = tid; idx < 2 * 64 * 64; idx += 512) {
                int l = idx & 63, kt = (idx >> 6) & 63, m2 = idx >> 12;
                int m = l & 15;
                int gate = m2 * 2 + (m >> 3);
                int row  = gate * HID + blk * 8 + (m & 7);
                int colw = kt * 32 + (l >> 4) * 8;
                const float4* p = (const float4*)(wih + (size_t)row * HID + colw);
                float4 a = p[0], b = p[1];
                half8 v = Wlds[idx];
                v[0] = (_Float16)((float)v[0] + a.x); v[1] = (_Float16)((float)v[1] + a.y);
                v[2] = (_Float16)((float)v[2] + a.z); v[3] = (_Float16)((float)v[3] + a.w);
                v[4] = (_Float16)((float)v[4] + b.x); v[5] = (_Float16)((float)v[5] + b.y);
                v[6] = (_Float16)((float)v[6] + b.z); v[7] = (_Float16)((float)v[7] + b.w);
                Wlds[idx] = v;
            }
            __syncthreads();
        }
    }
}

// ---- final: out[b][t] = bout + sum over 256 CU partials ----
__global__ __launch_bounds__(512)
void k_yout(const float* __restrict__ ypart, const float* __restrict__ bout,
            float* __restrict__ out, int steps) {
    __shared__ float red[8][64];
    int t = blockIdx.x;
    int tid = threadIdx.x;
    int b = tid & 63, ch = tid >> 6;               // 8 chunks x 32 CUs
    const float* p = ypart + (size_t)t * NCU * 64 + b;
    float s = 0.0f;
    #pragma unroll 8
    for (int cu = ch * 32; cu < ch * 32 + 32; ++cu) s += p[(size_t)cu * 64];
    red[ch][b] = s;
    __syncthreads();
    if (tid < 64) {
        float r = bout[0];
        #pragma unroll
        for (int u = 0; u < 8; ++u) r += red[u][tid];
        out[(size_t)tid * steps + t] = r;
    }
}

extern "C" void kernel_launch(void* const* d_in, const int* in_sizes, int n_in,
                              void* d_out, int out_size, void* d_ws, size_t ws_size,
                              hipStream_t stream) {
    const float* token = (const float*)d_in[0];
    const float* wih   = (const float*)d_in[2];
    const float* whh   = (const float*)d_in[3];
    const float* bih   = (const float*)d_in[4];
    const float* bhh   = (const float*)d_in[5];
    const float* wout  = (const float*)d_in[6];
    const float* bout  = (const float*)d_in[7];
    float* out = (float*)d_out;
    const int steps = out_size / BATCH;            // 30

    char* ws = (char*)d_ws;
    size_t off = 0;
    auto carve = [&](size_t bytes) -> void* {
        void* p = ws + off;
        off = (off + bytes + 255) & ~(size_t)255;
        return p;
    };
    _Float16* hbuf  = (_Float16*)carve((size_t)(steps + 1) * HID * BATCH * 2); // ~8 MB
    float*    bsum  = (float*)carve((size_t)G4 * 4);                   // 32 KB
    float*    ypart = (float*)carve((size_t)steps * NCU * 64 * 4);     // ~2 MB
    unsigned* flags = (unsigned*)carve(NFLAGS * 4);

    hipFuncSetAttribute(reinterpret_cast<const void*>(&k_lstm),
                        hipFuncAttributeMaxDynamicSharedMemorySize, LDS_BYTES);

    k_init<<<dim3(HGRP / 256), dim3(256), 0, stream>>>(
        token, bih, bhh, (half8*)hbuf, bsum, flags);

    k_lstm<<<dim3(NCU), dim3(512), LDS_BYTES, stream>>>(
        wih, whh, bsum, wout, hbuf, ypart, flags, steps);

    k_yout<<<dim3(steps), dim3(512), 0, stream>>>(ypart, bout, out, steps);
}